// Round 2
// baseline (621.817 us; speedup 1.0000x reference)
//
#include <hip/hip_runtime.h>
#include <hip/hip_bf16.h>

#define NN 100000
#define EE 1000000
// IN_CH = HID = 256 hard-coded throughout.

typedef short bf16x8 __attribute__((ext_vector_type(8)));
typedef float f32x4 __attribute__((ext_vector_type(4)));

__device__ __forceinline__ unsigned short f2bf_rne(float f) {
    unsigned int u = __builtin_bit_cast(unsigned int, f);
    u = u + 0x7fffu + ((u >> 16) & 1u);
    return (unsigned short)(u >> 16);
}

// product of two bf16 pairs (packed in dwords), repacked to bf16 pair (truncation)
__device__ __forceinline__ unsigned int bfprod2(unsigned int a, unsigned int b) {
    float alo = __builtin_bit_cast(float, a << 16);
    float ahi = __builtin_bit_cast(float, a & 0xffff0000u);
    float blo = __builtin_bit_cast(float, b << 16);
    float bhi = __builtin_bit_cast(float, b & 0xffff0000u);
    unsigned int lo = __builtin_bit_cast(unsigned int, alo * blo);
    unsigned int hi = __builtin_bit_cast(unsigned int, ahi * bhi);
    return __builtin_amdgcn_perm(hi, lo, 0x07060302u); // [hi.b3 hi.b2 lo.b3 lo.b2]
}

__device__ __forceinline__ unsigned int packtrunc(float lo, float hi) {
    return __builtin_amdgcn_perm(__builtin_bit_cast(unsigned int, hi),
                                 __builtin_bit_cast(unsigned int, lo), 0x07060302u);
}

template<int CTRL>
__device__ __forceinline__ float dpp_add(float v) {
    int s = __builtin_bit_cast(int, v);
    int m = __builtin_amdgcn_mov_dpp(s, CTRL, 0xF, 0xF, true);
    return v + __builtin_bit_cast(float, m);
}
// sum across the 16 lanes of a DPP row (VALU pipe, no LDS traffic)
__device__ __forceinline__ float red16(float v) {
    v = dpp_add<0xB1>(v);   // quad_perm [1,0,3,2]  (xor 1)
    v = dpp_add<0x4E>(v);   // quad_perm [2,3,0,1]  (xor 2)
    v = dpp_add<0x124>(v);  // row_ror:4
    v = dpp_add<0x128>(v);  // row_ror:8
    return v;
}

// W1 [k=256][c=256] f32  ->  W1T [c][k] bf16 (RNE)
__global__ void k_w1t(const float* __restrict__ W1, unsigned short* __restrict__ w1t) {
    int c = blockIdx.x, k = threadIdx.x;
    w1t[c * 256 + k] = f2bf_rne(W1[k * 256 + c]);
}

// z f32 -> bf16 (RNE), 8 elems/thread, exact grid (25.6e6 / 8 / 256 = 12500)
__global__ void k_zconv(const float* __restrict__ z, unsigned short* __restrict__ z16) {
    long long i = ((long long)blockIdx.x * 256 + threadIdx.x) * 8;
    float4 a = *(const float4*)(z + i);
    float4 b = *(const float4*)(z + i + 4);
    uint4 o;
    o.x = (unsigned)f2bf_rne(a.x) | ((unsigned)f2bf_rne(a.y) << 16);
    o.y = (unsigned)f2bf_rne(a.z) | ((unsigned)f2bf_rne(a.w) << 16);
    o.z = (unsigned)f2bf_rne(b.x) | ((unsigned)f2bf_rne(b.y) << 16);
    o.w = (unsigned)f2bf_rne(b.z) | ((unsigned)f2bf_rne(b.w) << 16);
    *(uint4*)(z16 + i) = o;
}

// Fused: gather+product -> x tile (LDS, bf16) -> MFMA vs W1 -> relu -> dot W2 -> sigmoid
// 512 threads = 8 waves as 2(M) x 4(N); 128 edges/block.
// x LDS row stride 528 B (512 + 16 pad) -> b128 reads hit the 8-slot conflict floor.
template<bool Z16>
__global__ __launch_bounds__(512, 2)
void k_main(const float* __restrict__ zf,
            const unsigned short* __restrict__ z16,
            const int* __restrict__ src, const int* __restrict__ dst,
            const unsigned short* __restrict__ w1t,
            const float* __restrict__ b1, const float* __restrict__ w2,
            const float* __restrict__ b2p, float* __restrict__ out)
{
    __shared__ __align__(16) char xs[128 * 528];
    __shared__ float part[4][128];

    const int t = threadIdx.x;
    const int e0 = blockIdx.x * 128;
    const int lane = t & 63;
    const int w = t >> 6;
    const int wm = w >> 2, wn = w & 3;       // M-half, N-quarter
    const int lr = lane & 15, lg = lane >> 4;

    // ---- B fragments: full per-wave W1T chunk held in registers (loaded once) ----
    // B layout (16x16x32): col = lane&15, k = (lane>>4)*8 + j ; W1T is [col][k] contiguous.
    bf16x8 B[4][8];
    float b1r[4], w2r[4];
    #pragma unroll
    for (int n = 0; n < 4; ++n) {
        const int col = wn * 64 + n * 16 + lr;
        const short* rp = (const short*)w1t + col * 256 + lg * 8;
        #pragma unroll
        for (int kk = 0; kk < 8; ++kk)
            B[n][kk] = *(const bf16x8*)(rp + kk * 32);
        b1r[n] = b1[col];
        w2r[n] = w2[col];
    }

    // ---- stage x tile: 4 threads per edge, 64 ch each ----
    {
        const int el = t >> 2, q = t & 3;
        int e = e0 + el; if (e >= EE) e = EE - 1;   // tail clamp (store masked later)
        const int s = src[e], d = dst[e];
        unsigned int* xw = (unsigned int*)(xs + el * 528 + q * 128);
        if (Z16) {
            const uint4* sp = (const uint4*)(z16 + s * 256 + q * 64);
            const uint4* dp = (const uint4*)(z16 + d * 256 + q * 64);
            #pragma unroll
            for (int i = 0; i < 8; ++i) {
                uint4 a = sp[i], b = dp[i];
                uint4 x;
                x.x = bfprod2(a.x, b.x);
                x.y = bfprod2(a.y, b.y);
                x.z = bfprod2(a.z, b.z);
                x.w = bfprod2(a.w, b.w);
                *(uint4*)(xw + i * 4) = x;
            }
        } else {
            const float4* sp = (const float4*)(zf + s * 256 + q * 64);
            const float4* dp = (const float4*)(zf + d * 256 + q * 64);
            #pragma unroll
            for (int i = 0; i < 16; i += 2) {
                float4 a0 = sp[i], a1 = sp[i + 1];
                float4 c0 = dp[i], c1 = dp[i + 1];
                uint4 x;
                x.x = packtrunc(a0.x * c0.x, a0.y * c0.y);
                x.y = packtrunc(a0.z * c0.z, a0.w * c0.w);
                x.z = packtrunc(a1.x * c1.x, a1.y * c1.y);
                x.w = packtrunc(a1.z * c1.z, a1.w * c1.w);
                *(uint4*)(xw + (i / 2) * 4) = x;
            }
        }
    }
    __syncthreads();

    // ---- per-wave: 4 M-tiles x 4 N-tiles x 8 K-steps ----
    #pragma unroll
    for (int m = 0; m < 4; ++m) {
        // A layout: row = lane&15, k = (lane>>4)*8 + j
        const char* ap = xs + (wm * 64 + m * 16 + lr) * 528 + lg * 16;
        bf16x8 A[8];
        #pragma unroll
        for (int kk = 0; kk < 8; ++kk)
            A[kk] = *(const bf16x8*)(ap + kk * 64);
        f32x4 acc[4];
        #pragma unroll
        for (int n = 0; n < 4; ++n) acc[n] = (f32x4){0.f, 0.f, 0.f, 0.f};
        #pragma unroll
        for (int kk = 0; kk < 8; ++kk) {
            #pragma unroll
            for (int n = 0; n < 4; ++n)   // 4 independent acc chains hide MFMA latency
                acc[n] = __builtin_amdgcn_mfma_f32_16x16x32_bf16(A[kk], B[n][kk], acc[n], 0, 0, 0);
        }
        // epilogue: relu(h + b1) * w2, summed over this wave's 64 cols
        float pr[4] = {0.f, 0.f, 0.f, 0.f};
        #pragma unroll
        for (int n = 0; n < 4; ++n) {
            #pragma unroll
            for (int r = 0; r < 4; ++r) {
                float h = acc[n][r] + b1r[n];   // C layout: col=lane&15, row=(lane>>4)*4+r
                h = fmaxf(h, 0.f);
                pr[r] = fmaf(h, w2r[n], pr[r]);
            }
        }
        #pragma unroll
        for (int r = 0; r < 4; ++r) pr[r] = red16(pr[r]);  // sum over 16 cols (lanes)
        if (lr == 0) {
            const int er = wm * 64 + m * 16 + lg * 4;
            part[wn][er + 0] = pr[0];
            part[wn][er + 1] = pr[1];
            part[wn][er + 2] = pr[2];
            part[wn][er + 3] = pr[3];
        }
    }
    __syncthreads();

    // ---- cross-wave (N) reduce + bias + sigmoid ----
    if (t < 128) {
        float s = b2p[0] + part[0][t] + part[1][t] + part[2][t] + part[3][t];
        float o = 1.f / (1.f + __expf(-s));
        const int e = e0 + t;
        if (e < EE) out[e] = o;
    }
}

extern "C" void kernel_launch(void* const* d_in, const int* in_sizes, int n_in,
                              void* d_out, int out_size, void* d_ws, size_t ws_size,
                              hipStream_t stream) {
    const float* z  = (const float*)d_in[0];
    const int* src  = (const int*)d_in[1];
    const int* dst  = (const int*)d_in[2];
    const float* W1 = (const float*)d_in[3];
    const float* b1 = (const float*)d_in[4];
    const float* W2 = (const float*)d_in[5];
    const float* b2 = (const float*)d_in[6];
    float* out = (float*)d_out;

    const size_t z16_bytes = (size_t)NN * 256 * 2;   // 51.2 MB
    const size_t w1t_bytes = 256 * 256 * 2;          // 128 KB
    const bool use_z16 = ws_size >= z16_bytes + w1t_bytes;

    unsigned short* z16 = (unsigned short*)d_ws;
    unsigned short* w1t = use_z16 ? (unsigned short*)((char*)d_ws + z16_bytes)
                                  : (unsigned short*)d_ws;

    // ws is re-poisoned every launch: rebuild both every call.
    k_w1t<<<256, 256, 0, stream>>>(W1, w1t);
    const int grid = (EE + 127) / 128;   // 7813
    if (use_z16) {
        k_zconv<<<12500, 256, 0, stream>>>(z, z16);
        k_main<true><<<grid, 512, 0, stream>>>(z, z16, src, dst, w1t, b1, W2, b2, out);
    } else {
        k_main<false><<<grid, 512, 0, stream>>>(z, (const unsigned short*)nullptr,
                                                src, dst, w1t, b1, W2, b2, out);
    }
}

// Round 3
// 372.400 us; speedup vs baseline: 1.6698x; 1.6698x over previous
//
#include <hip/hip_runtime.h>
#include <hip/hip_bf16.h>

#define NN 100000
#define EE 1000000
#define NCH 15625          // EE / 64 exactly
#define NBLK 256           // persistent: 1 block per CU
#define PITCH 528          // 512 + 16B pad: even 8-lane/bank spread for b128

typedef short bf16x8 __attribute__((ext_vector_type(8)));
typedef float f32x4 __attribute__((ext_vector_type(4)));

__device__ __forceinline__ unsigned short f2bf_rne(float f) {
    unsigned int u = __builtin_bit_cast(unsigned int, f);
    u = u + 0x7fffu + ((u >> 16) & 1u);
    return (unsigned short)(u >> 16);
}

// product of two bf16 pairs (packed dwords) -> bf16 pair (truncation)
__device__ __forceinline__ unsigned int bfprod2(unsigned int a, unsigned int b) {
    float alo = __builtin_bit_cast(float, a << 16);
    float ahi = __builtin_bit_cast(float, a & 0xffff0000u);
    float blo = __builtin_bit_cast(float, b << 16);
    float bhi = __builtin_bit_cast(float, b & 0xffff0000u);
    unsigned int lo = __builtin_bit_cast(unsigned int, alo * blo);
    unsigned int hi = __builtin_bit_cast(unsigned int, ahi * bhi);
    return __builtin_amdgcn_perm(hi, lo, 0x07060302u);
}

__device__ __forceinline__ unsigned int packtrunc(float lo, float hi) {
    return __builtin_amdgcn_perm(__builtin_bit_cast(unsigned int, hi),
                                 __builtin_bit_cast(unsigned int, lo), 0x07060302u);
}

template<int CTRL>
__device__ __forceinline__ float dpp_add(float v) {
    int s = __builtin_bit_cast(int, v);
    int m = __builtin_amdgcn_mov_dpp(s, CTRL, 0xF, 0xF, true);
    return v + __builtin_bit_cast(float, m);
}
__device__ __forceinline__ float red16(float v) {   // sum over 16-lane row (VALU pipe)
    v = dpp_add<0xB1>(v);
    v = dpp_add<0x4E>(v);
    v = dpp_add<0x124>(v);
    v = dpp_add<0x128>(v);
    return v;
}

// W1 [k][c] f32 -> W1T [c][k] bf16
__global__ void k_w1t(const float* __restrict__ W1, unsigned short* __restrict__ w1t) {
    int c = blockIdx.x, k = threadIdx.x;
    w1t[c * 256 + k] = f2bf_rne(W1[k * 256 + c]);
}

__global__ void k_zconv(const float* __restrict__ z, unsigned short* __restrict__ z16) {
    long long i = ((long long)blockIdx.x * 256 + threadIdx.x) * 8;
    float4 a = *(const float4*)(z + i);
    float4 b = *(const float4*)(z + i + 4);
    uint4 o;
    o.x = (unsigned)f2bf_rne(a.x) | ((unsigned)f2bf_rne(a.y) << 16);
    o.y = (unsigned)f2bf_rne(a.z) | ((unsigned)f2bf_rne(a.w) << 16);
    o.z = (unsigned)f2bf_rne(b.x) | ((unsigned)f2bf_rne(b.y) << 16);
    o.w = (unsigned)f2bf_rne(b.z) | ((unsigned)f2bf_rne(b.w) << 16);
    *(uint4*)(z16 + i) = o;
}

// Persistent fused kernel: 256 blocks x 512 threads (8 waves: 2M x 4N).
// B (W1T 64-col slice, full K) pinned in VGPRs for the whole kernel.
// Chunks of 64 edges, double-buffered LDS, async-split staging.
template<bool Z16>
__global__ __launch_bounds__(512, 2)
void k_main(const float* __restrict__ zf,
            const unsigned short* __restrict__ z16,
            const int* __restrict__ src, const int* __restrict__ dst,
            const unsigned short* __restrict__ w1t,
            const float* __restrict__ b1, const float* __restrict__ w2,
            const float* __restrict__ b2p, float* __restrict__ out)
{
    __shared__ __align__(16) char xs[2][64 * PITCH];   // 2 x 33792 B
    __shared__ float part[2][4][64];                   // 2 KB

    const int t = threadIdx.x;
    const int lane = t & 63;
    const int w = t >> 6;
    const int wm = w >> 2, wn = w & 3;      // M-half, N-quarter
    const int lr = lane & 15, lg = lane >> 4;

    // ---- B: wave's 64 W1T cols, full K=256, held in registers for the whole kernel ----
    bf16x8 B[4][8];
    float b1r[4], w2r[4];
    #pragma unroll
    for (int n = 0; n < 4; ++n) {
        const int col = wn * 64 + n * 16 + lr;
        const short* rp = (const short*)w1t + col * 256 + lg * 8;
        #pragma unroll
        for (int kk = 0; kk < 8; ++kk)
            B[n][kk] = *(const bf16x8*)(rp + kk * 32);
        b1r[n] = b1[col];
        w2r[n] = w2[col];
    }
    // pin: forbid the compiler from sinking/rematerializing the B loads
    #pragma unroll
    for (int n = 0; n < 4; ++n)
        #pragma unroll
        for (int kk = 0; kk < 8; ++kk)
            asm volatile("" : "+v"(B[n][kk]));

    const float b2s = b2p[0];
    const int el = t >> 3, q = t & 7;       // 8 threads/edge, 32 ch each

    uint4 ga[4], gb[4];                     // staged gather regs (bf16 path)

    // issue gather loads for chunk c (no wait — results consumed in product_store)
    auto stage_load = [&](int c) {
        const int e = c * 64 + el;
        const int s = src[e], d = dst[e];
        const uint4* sp = (const uint4*)(z16 + s * 256 + q * 32);
        const uint4* dp = (const uint4*)(z16 + d * 256 + q * 32);
        ga[0] = sp[0]; ga[1] = sp[1]; ga[2] = sp[2]; ga[3] = sp[3];
        gb[0] = dp[0]; gb[1] = dp[1]; gb[2] = dp[2]; gb[3] = dp[3];
    };
    auto product_store = [&](int p) {
        unsigned int* xw = (unsigned int*)(xs[p] + el * PITCH + q * 64);
        #pragma unroll
        for (int i = 0; i < 4; ++i) {
            uint4 x;
            x.x = bfprod2(ga[i].x, gb[i].x);
            x.y = bfprod2(ga[i].y, gb[i].y);
            x.z = bfprod2(ga[i].z, gb[i].z);
            x.w = bfprod2(ga[i].w, gb[i].w);
            *(uint4*)(xw + i * 4) = x;
        }
    };
    // f32 fallback: load + product + store in one step (no async split)
    auto stage_f32 = [&](int c, int p) {
        const int e = c * 64 + el;
        const int s = src[e], d = dst[e];
        const float4* sp = (const float4*)(zf + s * 256 + q * 32);
        const float4* dp = (const float4*)(zf + d * 256 + q * 32);
        unsigned int* xw = (unsigned int*)(xs[p] + el * PITCH + q * 64);
        #pragma unroll
        for (int i = 0; i < 4; ++i) {
            float4 a0 = sp[2 * i], a1 = sp[2 * i + 1];
            float4 c0 = dp[2 * i], c1 = dp[2 * i + 1];
            uint4 x;
            x.x = packtrunc(a0.x * c0.x, a0.y * c0.y);
            x.y = packtrunc(a0.z * c0.z, a0.w * c0.w);
            x.z = packtrunc(a1.x * c1.x, a1.y * c1.y);
            x.w = packtrunc(a1.z * c1.z, a1.w * c1.w);
            *(uint4*)(xw + i * 4) = x;
        }
    };
    // compute chunk from buf p: 2 m-tiles/wave, MFMA + fused relu/W2 epilogue -> part[p]
    auto compute = [&](int p) {
        #pragma unroll
        for (int mi = 0; mi < 2; ++mi) {
            const int mt = wm * 2 + mi;
            const char* ap = xs[p] + (mt * 16 + lr) * PITCH + lg * 16;
            bf16x8 A[8];
            #pragma unroll
            for (int kk = 0; kk < 8; ++kk)
                A[kk] = *(const bf16x8*)(ap + kk * 64);
            f32x4 acc[4];
            #pragma unroll
            for (int n = 0; n < 4; ++n) acc[n] = (f32x4){0.f, 0.f, 0.f, 0.f};
            #pragma unroll
            for (int kk = 0; kk < 8; ++kk) {
                #pragma unroll
                for (int n = 0; n < 4; ++n)
                    acc[n] = __builtin_amdgcn_mfma_f32_16x16x32_bf16(A[kk], B[n][kk], acc[n], 0, 0, 0);
            }
            float pr[4] = {0.f, 0.f, 0.f, 0.f};
            #pragma unroll
            for (int n = 0; n < 4; ++n) {
                #pragma unroll
                for (int r = 0; r < 4; ++r) {
                    float h = fmaxf(acc[n][r] + b1r[n], 0.f);   // col=lane&15, row=lg*4+r
                    pr[r] = fmaf(h, w2r[n], pr[r]);
                }
            }
            #pragma unroll
            for (int r = 0; r < 4; ++r) pr[r] = red16(pr[r]);
            if (lr == 0) {
                const int er = mt * 16 + lg * 4;
                part[p][wn][er + 0] = pr[0];
                part[p][wn][er + 1] = pr[1];
                part[p][wn][er + 2] = pr[2];
                part[p][wn][er + 3] = pr[3];
            }
        }
    };

    // ---- persistent chunk loop (grid-stride 256) ----
    int c = blockIdx.x;
    int p = 0;
    if (Z16) { stage_load(c); product_store(0); }
    else     { stage_f32(c, 0); }
    __syncthreads();

    while (true) {
        const int cn = c + NBLK;
        const bool hn = cn < NCH;
        if (Z16) {
            if (hn) stage_load(cn);       // issue gathers: latency hides under compute
            compute(p);
            if (hn) product_store(p ^ 1); // vmcnt drain + product + LDS write
        } else {
            compute(p);
            if (hn) stage_f32(cn, p ^ 1);
        }
        __syncthreads();
        // cross-wave N-reduce + bias + sigmoid for chunk c
        if (t < 64) {
            float s = b2s + part[p][0][t] + part[p][1][t] + part[p][2][t] + part[p][3][t];
            out[c * 64 + t] = 1.f / (1.f + __expf(-s));
        }
        if (!hn) break;
        p ^= 1;
        c = cn;
    }
}

extern "C" void kernel_launch(void* const* d_in, const int* in_sizes, int n_in,
                              void* d_out, int out_size, void* d_ws, size_t ws_size,
                              hipStream_t stream) {
    const float* z  = (const float*)d_in[0];
    const int* src  = (const int*)d_in[1];
    const int* dst  = (const int*)d_in[2];
    const float* W1 = (const float*)d_in[3];
    const float* b1 = (const float*)d_in[4];
    const float* W2 = (const float*)d_in[5];
    const float* b2 = (const float*)d_in[6];
    float* out = (float*)d_out;

    const size_t z16_bytes = (size_t)NN * 256 * 2;   // 51.2 MB
    const size_t w1t_bytes = 256 * 256 * 2;          // 128 KB
    const bool use_z16 = ws_size >= z16_bytes + w1t_bytes;

    unsigned short* z16 = (unsigned short*)d_ws;
    unsigned short* w1t = use_z16 ? (unsigned short*)((char*)d_ws + z16_bytes)
                                  : (unsigned short*)d_ws;

    k_w1t<<<256, 256, 0, stream>>>(W1, w1t);
    if (use_z16) {
        k_zconv<<<12500, 256, 0, stream>>>(z, z16);
        k_main<true><<<NBLK, 512, 0, stream>>>(z, z16, src, dst, w1t, b1, W2, b2, out);
    } else {
        k_main<false><<<NBLK, 512, 0, stream>>>(z, (const unsigned short*)nullptr,
                                                src, dst, w1t, b1, W2, b2, out);
    }
}